// Round 6
// baseline (700.672 us; speedup 1.0000x reference)
//
#include <hip/hip_runtime.h>
#include <hip/hip_bf16.h>
#include <cstddef>

#define H 200
#define NA 48
#define NBB 96
#define BATCH 128
#define AFD 39
#define BFD 50          // 39+11
#define LP 1000
#define CATD (AFD + H)  // 239
#define BPB 4
#define APB 2
#define BIPB 4

typedef unsigned short ushort_t;
typedef __bf16 bf16x8 __attribute__((ext_vector_type(8)));
typedef float f32x16 __attribute__((ext_vector_type(16)));

union U16B { uint4 u; bf16x8 b; };
static __device__ __forceinline__ bf16x8 as_bf16x8(uint4 u) { U16B x; x.u = u; return x.b; }

static __device__ __forceinline__ ushort_t f2bf(float f) {
    union { float f; unsigned u; } a; a.f = f;
    unsigned r = (a.u + 0x7FFFu + ((a.u >> 16) & 1u)) >> 16;
    return (ushort_t)r;
}

static __device__ __forceinline__ f32x16 mfma32(uint4 a, uint4 b, f32x16 c) {
    return __builtin_amdgcn_mfma_f32_32x32x16_bf16(as_bf16x8(a), as_bf16x8(b), c, 0, 0, 0);
}

// ---------------- fused prep: 3 weight swizzles (32x32x16 A-frag order) + zero x ----------------
template <int COUT, int CIN, int CP, int K>
static __device__ __forceinline__ void prep_one(int t, const float* __restrict__ w,
                                                ushort_t* __restrict__ Wb) {
    constexpr int NC = CP / 16;
    constexpr int NS = K * NC;
    int j = t & 7;
    int lane = (t >> 3) & 63;
    int s = (t >> 9) % NS;
    int ct = (t >> 9) / NS;
    int co = ct * 32 + (lane & 31);
    int tt = s / NC, cc = s % NC;
    int ci = cc * 16 + ((lane >> 5) & 1) * 8 + j;
    float v = 0.f;
    if (co < COUT && ci < CIN) v = w[((size_t)co * CIN + ci) * K + tt];
    Wb[t] = f2bf(v);
}

#define PREP_T0 (4 * 12 * 512)
#define PREP_T1 (PREP_T0 + 4 * 30 * 512)
#define PREP_T2 (PREP_T1 + 8 * 56 * 512)
#define PREP_T3 (PREP_T2 + 51200)

__global__ __launch_bounds__(256) void k_prep_all(
        const float* __restrict__ c0w, const float* __restrict__ c1w,
        const float* __restrict__ c2w, float* __restrict__ x,
        ushort_t* __restrict__ Wb0, ushort_t* __restrict__ Wb1,
        ushort_t* __restrict__ Wb2) {
    int tid = blockIdx.x * 256 + threadIdx.x;
    if (tid < PREP_T0) prep_one<96, 50, 64, 3>(tid, c0w, Wb0);
    else if (tid < PREP_T1) prep_one<128, 96, 96, 5>(tid - PREP_T0, c1w, Wb1);
    else if (tid < PREP_T2) prep_one<200, 128, 128, 7>(tid - PREP_T1, c2w, Wb2);
    else if (tid < PREP_T3) x[tid - PREP_T2] = 0.f;
}

// ---------------- MEGA-FUSED protein tower: embed -> conv0 -> conv1 -> conv2+maxpool ----------
// One block = one molecule x 64 output positions. All activations flow through LDS.
// X0: 76 rows x pitch 72 (64ch)   @ 0       (5472 ushorts)
// X1: 74 rows x pitch 104 (96ch)  @ 9728
// X2: 70 rows x pitch 136 (128ch) @ 0       (overlays dead X0; 9520 <= 9728)
// Total 34848 B -> 4 blocks/CU.
#define X1OFF 9728
#define XS_TOT (X1OFF + 74 * 104)

__global__ __launch_bounds__(256, 4) void k_megaconv(
        const int* __restrict__ seq, const float* __restrict__ emb,
        const ushort_t* __restrict__ Wb0, const ushort_t* __restrict__ Wb1,
        const ushort_t* __restrict__ Wb2,
        const float* __restrict__ b0, const float* __restrict__ b1,
        const float* __restrict__ b2, float* __restrict__ x) {
    __shared__ __align__(16) ushort_t Xs[XS_TOT];

    int lb = blockIdx.x, b = blockIdx.y;
    int l0 = lb * 64;
    int tid = threadIdx.x;
    int lane = tid & 63, wv = tid >> 6;
    int ln31 = lane & 31, half = lane >> 5;

    // ---- phase E: embed rows [l0-6, l0+70) -> X0 (ch 50..63 zero) ----
    {
        const int* seqb = seq + (size_t)b * LP;
        for (int idx = tid; idx < 76 * 8; idx += 256) {
            int r = idx >> 3, c = idx & 7;
            int l = l0 - 6 + r;
            uint4 v = {0u, 0u, 0u, 0u};
            if ((unsigned)l < (unsigned)LP) {
                const float* e = emb + (size_t)seqb[l] * 50;
                ushort_t h[8];
#pragma unroll
                for (int j = 0; j < 8; ++j) {
                    int cc = c * 8 + j;
                    h[j] = (cc < 50) ? f2bf(e[cc]) : (ushort_t)0;
                }
                v.x = (unsigned)h[0] | ((unsigned)h[1] << 16);
                v.y = (unsigned)h[2] | ((unsigned)h[3] << 16);
                v.z = (unsigned)h[4] | ((unsigned)h[5] << 16);
                v.w = (unsigned)h[6] | ((unsigned)h[7] << 16);
            }
            *(uint4*)(Xs + r * 72 + c * 8) = v;
        }
    }
    __syncthreads();

    // ---- phase 0: conv0 (50->96, K=3, NS=12). 9 units = 3 co-tiles x 3 l-tiles ----
#pragma unroll
    for (int ui = 0; ui < 3; ++ui) {
        int u = wv + ui * 4;
        if (u < 9) {
            int cot = u / 3, lt = u % 3;
            f32x16 acc;
#pragma unroll
            for (int r = 0; r < 16; ++r) acc[r] = 0.f;
#pragma unroll
            for (int s = 0; s < 12; ++s) {
                int t = s >> 2, cc = s & 3;
                int brow = lt * 32 + ln31 + t;
                brow = (brow < 75) ? brow : 75;
                uint4 av = ((const uint4*)Wb0)[((size_t)(cot * 12 + s)) * 64 + lane];
                uint4 bv = *(const uint4*)(Xs + brow * 72 + cc * 16 + half * 8);
                acc = mfma32(av, bv, acc);
            }
            int r1 = lt * 32 + ln31;
            if (r1 < 74) {
                int l = l0 - 5 + r1;
                bool in = (unsigned)l < (unsigned)LP;
                int cbase = cot * 32 + 4 * half;
#pragma unroll
                for (int g = 0; g < 4; ++g) {
                    int co = cbase + 8 * g;
                    float4 bb = *(const float4*)(b0 + co);
                    ushort_t h0 = in ? f2bf(fmaxf(acc[4 * g + 0] + bb.x, 0.f)) : (ushort_t)0;
                    ushort_t h1 = in ? f2bf(fmaxf(acc[4 * g + 1] + bb.y, 0.f)) : (ushort_t)0;
                    ushort_t h2 = in ? f2bf(fmaxf(acc[4 * g + 2] + bb.z, 0.f)) : (ushort_t)0;
                    ushort_t h3 = in ? f2bf(fmaxf(acc[4 * g + 3] + bb.w, 0.f)) : (ushort_t)0;
                    uint2 o;
                    o.x = (unsigned)h0 | ((unsigned)h1 << 16);
                    o.y = (unsigned)h2 | ((unsigned)h3 << 16);
                    *(uint2*)(Xs + X1OFF + r1 * 104 + co) = o;
                }
            }
        }
    }
    __syncthreads();

    // ---- phase 1: conv1 (96->128, K=5, NS=30). 12 units = 4 co-tiles x 3 l-tiles ----
#pragma unroll
    for (int ui = 0; ui < 3; ++ui) {
        int u = wv + ui * 4;  // u < 12 always
        int cot = u & 3, lt = u >> 2;
        f32x16 acc;
#pragma unroll
        for (int r = 0; r < 16; ++r) acc[r] = 0.f;
#pragma unroll
        for (int s = 0; s < 30; ++s) {
            int t = s / 6, cc = s % 6;
            int brow = lt * 32 + ln31 + t;
            brow = (brow < 73) ? brow : 73;
            uint4 av = ((const uint4*)Wb1)[((size_t)(cot * 30 + s)) * 64 + lane];
            uint4 bv = *(const uint4*)(Xs + X1OFF + brow * 104 + cc * 16 + half * 8);
            acc = mfma32(av, bv, acc);
        }
        int r2 = lt * 32 + ln31;
        if (r2 < 70) {
            int l = l0 - 3 + r2;
            bool in = (unsigned)l < (unsigned)LP;
            int cbase = cot * 32 + 4 * half;
#pragma unroll
            for (int g = 0; g < 4; ++g) {
                int co = cbase + 8 * g;
                float4 bb = *(const float4*)(b1 + co);
                ushort_t h0 = in ? f2bf(fmaxf(acc[4 * g + 0] + bb.x, 0.f)) : (ushort_t)0;
                ushort_t h1 = in ? f2bf(fmaxf(acc[4 * g + 1] + bb.y, 0.f)) : (ushort_t)0;
                ushort_t h2 = in ? f2bf(fmaxf(acc[4 * g + 2] + bb.z, 0.f)) : (ushort_t)0;
                ushort_t h3 = in ? f2bf(fmaxf(acc[4 * g + 3] + bb.w, 0.f)) : (ushort_t)0;
                uint2 o;
                o.x = (unsigned)h0 | ((unsigned)h1 << 16);
                o.y = (unsigned)h2 | ((unsigned)h3 << 16);
                *(uint2*)(Xs + r2 * 136 + co) = o;
            }
        }
    }
    __syncthreads();

    // ---- phase 2: conv2 (128->200pad256, K=7, NS=56) + relu + global maxpool ----
    // 8 units = 4 co-pairs (ct=2 B-reuse) x 2 l-tiles; 2 units/wave.
#pragma unroll
    for (int ui = 0; ui < 2; ++ui) {
        int ug = wv * 2 + ui;
        int cop = ug >> 1, lt = ug & 1;
        f32x16 a2[2];
#pragma unroll
        for (int ct = 0; ct < 2; ++ct)
#pragma unroll
            for (int r = 0; r < 16; ++r) a2[ct][r] = 0.f;
#pragma unroll
        for (int s = 0; s < 56; ++s) {
            int t = s >> 3, cc = s & 7;
            int brow = lt * 32 + ln31 + t;  // <= 69, in range
            uint4 bv = *(const uint4*)(Xs + brow * 136 + cc * 16 + half * 8);
            uint4 av0 = ((const uint4*)Wb2)[((size_t)((cop * 2 + 0) * 56 + s)) * 64 + lane];
            uint4 av1 = ((const uint4*)Wb2)[((size_t)((cop * 2 + 1) * 56 + s)) * 64 + lane];
            a2[0] = mfma32(av0, bv, a2[0]);
            a2[1] = mfma32(av1, bv, a2[1]);
        }
        int rr = lt * 32 + ln31;
        bool in = (l0 + rr) < LP;
#pragma unroll
        for (int ct = 0; ct < 2; ++ct) {
            float mx[16];
#pragma unroll
            for (int r = 0; r < 16; ++r) mx[r] = in ? a2[ct][r] : -3.0e38f;
#pragma unroll
            for (int r = 0; r < 16; ++r) {
#pragma unroll
                for (int off = 1; off < 32; off <<= 1)
                    mx[r] = fmaxf(mx[r], __shfl_xor(mx[r], off, 64));
            }
            if (ln31 == 0) {
                int cbase = (cop * 2 + ct) * 32 + 4 * half;
#pragma unroll
                for (int r = 0; r < 16; ++r) {
                    int co = cbase + (r & 3) + 8 * (r >> 2);
                    if (co < 200) {
                        float v = fmaxf(mx[r] + b2[co], 0.f);
                        atomicMax((int*)&x[(size_t)b * 400 + 200 + co], __float_as_int(v));
                    }
                }
            }
        }
    }
}

// ---------------- binput = fbonds @ W_i ; msg = relu(binput) ----------------
__global__ __launch_bounds__(256) void k_bond_input(
        const float* __restrict__ fbonds, const float* __restrict__ Wi,
        float* __restrict__ binput, float* __restrict__ msg) {
    int bond0 = blockIdx.x * BIPB;
    __shared__ float fb[BIPB][BFD];
    int tid = threadIdx.x;
    if (tid < BIPB * BFD) fb[tid / BFD][tid % BFD] = fbonds[(size_t)bond0 * BFD + tid];
    __syncthreads();
    if (tid < H) {
        float acc[BIPB];
#pragma unroll
        for (int q = 0; q < BIPB; ++q) acc[q] = 0.f;
#pragma unroll 5
        for (int k = 0; k < BFD; ++k) {
            float w = Wi[k * H + tid];
#pragma unroll
            for (int q = 0; q < BIPB; ++q) acc[q] += fb[q][k] * w;
        }
#pragma unroll
        for (int q = 0; q < BIPB; ++q) {
            size_t o = (size_t)(bond0 + q) * H + tid;
            binput[o] = acc[q];
            msg[o] = fmaxf(acc[q], 0.f);
        }
    }
}

// ---------------- message update: msgOut = relu(binput + (sum nei) @ W_h) ----------------
__global__ __launch_bounds__(256) void k_msg(
        const float* __restrict__ msgIn, const float* __restrict__ binput,
        const int* __restrict__ bgraph, const float* __restrict__ Wh,
        float* __restrict__ msgOut) {
    const int grpPerMol = NBB / BPB;
    int b = blockIdx.x / grpPerMol;
    int grp = blockIdx.x % grpPerMol;
    int bond0 = grp * BPB;
    __shared__ int idxs[BPB * 6];
    __shared__ float nei[BPB][H];
    int tid = threadIdx.x;
    if (tid < BPB * 6) idxs[tid] = bgraph[((size_t)(b * NBB + bond0)) * 6 + tid];
    __syncthreads();
    if (tid < H) {
        const float* base = msgIn + (size_t)b * NBB * H;
#pragma unroll
        for (int q = 0; q < BPB; ++q) {
            float s = 0.f;
#pragma unroll
            for (int j = 0; j < 6; ++j) s += base[(size_t)idxs[q * 6 + j] * H + tid];
            nei[q][tid] = s;
        }
    }
    __syncthreads();
    if (tid < H) {
        float acc[BPB];
#pragma unroll
        for (int q = 0; q < BPB; ++q)
            acc[q] = binput[((size_t)(b * NBB + bond0 + q)) * H + tid];
#pragma unroll 4
        for (int hi = 0; hi < H; ++hi) {
            float w = Wh[hi * H + tid];
#pragma unroll
            for (int q = 0; q < BPB; ++q) acc[q] += nei[q][hi] * w;
        }
#pragma unroll
        for (int q = 0; q < BPB; ++q)
            msgOut[((size_t)(b * NBB + bond0 + q)) * H + tid] = fmaxf(acc[q], 0.f);
    }
}

// ---------------- atom head: relu(cat(fa, nei) @ W_o + b), mean -> x[:, :200] ----------------
__global__ __launch_bounds__(256) void k_atom(
        const float* __restrict__ msg, const float* __restrict__ fatoms,
        const int* __restrict__ agraph, const float* __restrict__ Wo,
        const float* __restrict__ Wob, float* __restrict__ x) {
    const int grpPerMol = NA / APB;
    int b = blockIdx.x / grpPerMol;
    int grp = blockIdx.x % grpPerMol;
    int atom0 = grp * APB;
    __shared__ int idxs[APB * 6];
    __shared__ float cat[APB][CATD];
    int tid = threadIdx.x;
    if (tid < APB * 6) idxs[tid] = agraph[((size_t)(b * NA + atom0)) * 6 + tid];
    if (tid >= 64 && tid < 64 + APB * AFD) {
        int t = tid - 64;
        int q = t / AFD, c = t % AFD;
        cat[q][c] = fatoms[((size_t)(b * NA + atom0 + q)) * AFD + c];
    }
    __syncthreads();
    if (tid < H) {
        const float* base = msg + (size_t)b * NBB * H;
#pragma unroll
        for (int q = 0; q < APB; ++q) {
            float s = 0.f;
#pragma unroll
            for (int j = 0; j < 6; ++j) s += base[(size_t)idxs[q * 6 + j] * H + tid];
            cat[q][AFD + tid] = s;
        }
    }
    __syncthreads();
    if (tid < H) {
        float bb = Wob[tid];
        float acc0 = bb, acc1 = bb;
#pragma unroll 4
        for (int k = 0; k < CATD; ++k) {
            float w = Wo[k * H + tid];
            acc0 += cat[0][k] * w;
            acc1 += cat[1][k] * w;
        }
        atomicAdd(&x[(size_t)b * 400 + tid],
                  (fmaxf(acc0, 0.f) + fmaxf(acc1, 0.f)) * (1.f / NA));
    }
}

// ---------------- fused FC head: 400 -> 200 -> 100 -> 1 ----------------
__global__ __launch_bounds__(256) void k_fc(
        const float* __restrict__ x,
        const float* __restrict__ w0, const float* __restrict__ b0,
        const float* __restrict__ w1, const float* __restrict__ b1,
        const float* __restrict__ w2, const float* __restrict__ b2,
        float* __restrict__ out) {
    int b = blockIdx.x, tid = threadIdx.x;
    __shared__ float xr[400];
    __shared__ float h1[200];
    __shared__ float h2[100];
    for (int i = tid; i < 400; i += 256) xr[i] = x[(size_t)b * 400 + i];
    __syncthreads();
    if (tid < 200) {
        float a = b0[tid];
#pragma unroll 4
        for (int k = 0; k < 400; ++k) a += xr[k] * w0[k * 200 + tid];
        h1[tid] = fmaxf(a, 0.f);
    }
    __syncthreads();
    if (tid < 100) {
        float a = b1[tid];
#pragma unroll 4
        for (int k = 0; k < 200; ++k) a += h1[k] * w1[k * 100 + tid];
        h2[tid] = fmaxf(a, 0.f);
    }
    __syncthreads();
    if (tid == 0) {
        float a = b2[0];
#pragma unroll 4
        for (int k = 0; k < 100; ++k) a += h2[k] * w2[k];
        out[b] = a;
    }
}

extern "C" void kernel_launch(void* const* d_in, const int* in_sizes, int n_in,
                              void* d_out, int out_size, void* d_ws, size_t ws_size,
                              hipStream_t stream) {
    const float* fatoms = (const float*)d_in[0];
    const float* fbonds = (const float*)d_in[1];
    const int* agraph = (const int*)d_in[2];
    const int* bgraph = (const int*)d_in[3];
    const int* seq = (const int*)d_in[4];
    const float* Wi = (const float*)d_in[5];
    const float* Wh = (const float*)d_in[6];
    const float* Wo = (const float*)d_in[7];
    const float* Wob = (const float*)d_in[8];
    const float* embp = (const float*)d_in[9];
    const float* c0w = (const float*)d_in[10];
    const float* c0b = (const float*)d_in[11];
    const float* c1w = (const float*)d_in[12];
    const float* c1b = (const float*)d_in[13];
    const float* c2w = (const float*)d_in[14];
    const float* c2b = (const float*)d_in[15];
    const float* fc0w = (const float*)d_in[16];
    const float* fc0b = (const float*)d_in[17];
    const float* fc1w = (const float*)d_in[18];
    const float* fc1b = (const float*)d_in[19];
    const float* fc2w = (const float*)d_in[20];
    const float* fc2b = (const float*)d_in[21];

    float* ws = (float*)d_ws;
    float* binput = ws;                    // 2457600
    float* msgA = binput + 2457600;        // 2457600
    float* msgB = msgA + 2457600;          // 2457600
    float* x = msgB + 2457600;             // 51200
    ushort_t* u = (ushort_t*)(x + 51200);  // bf16 region
    ushort_t* Wb0 = u;                     // 4*12*512  = 24576
    ushort_t* Wb1 = Wb0 + 24576;           // 4*30*512  = 61440
    ushort_t* Wb2 = Wb1 + 61440;           // 8*56*512  = 229376

    // fused: weight swizzles + zero x (k_atom atomicAdd / megaconv atomicMax need zeros)
    k_prep_all<<<(PREP_T3 + 255) / 256, 256, 0, stream>>>(c0w, c1w, c2w, x, Wb0, Wb1, Wb2);

    // ---- MPNN ----
    k_bond_input<<<BATCH * NBB / BIPB, 256, 0, stream>>>(fbonds, Wi, binput, msgA);
    k_msg<<<BATCH * NBB / BPB, 256, 0, stream>>>(msgA, binput, bgraph, Wh, msgB);
    k_msg<<<BATCH * NBB / BPB, 256, 0, stream>>>(msgB, binput, bgraph, Wh, msgA);
    k_atom<<<BATCH * NA / APB, 256, 0, stream>>>(msgA, fatoms, agraph, Wo, Wob, x);

    // ---- protein tower: single fused kernel ----
    k_megaconv<<<dim3(16, BATCH), 256, 0, stream>>>(seq, embp, Wb0, Wb1, Wb2,
                                                    c0b, c1b, c2b, x);

    // ---- fused FC head ----
    k_fc<<<BATCH, 256, 0, stream>>>(x, fc0w, fc0b, fc1w, fc1b, fc2w, fc2b, (float*)d_out);
}

// Round 7
// 417.992 us; speedup vs baseline: 1.6763x; 1.6763x over previous
//
#include <hip/hip_runtime.h>
#include <hip/hip_bf16.h>
#include <cstddef>

#define H 200
#define NA 48
#define NBB 96
#define BATCH 128
#define AFD 39
#define BFD 50          // 39+11
#define LP 1000
#define CATD (AFD + H)  // 239
#define BPB 4           // bonds per block in message kernel (BPB=8 spilled in R3)
#define APB 2           // atoms per block in atom kernel
#define BIPB 4          // bonds per block in bond-input kernel

typedef unsigned short ushort_t;
typedef __bf16 bf16x8 __attribute__((ext_vector_type(8)));
typedef float f32x16 __attribute__((ext_vector_type(16)));

union U16B { uint4 u; bf16x8 b; };
static __device__ __forceinline__ bf16x8 as_bf16x8(uint4 u) { U16B x; x.u = u; return x.b; }

// float -> bf16 (RNE)
static __device__ __forceinline__ ushort_t f2bf(float f) {
    union { float f; unsigned u; } a; a.f = f;
    unsigned r = (a.u + 0x7FFFu + ((a.u >> 16) & 1u)) >> 16;
    return (ushort_t)r;
}

static __device__ __forceinline__ f32x16 mfma32(uint4 a, uint4 b, f32x16 c) {
    return __builtin_amdgcn_mfma_f32_32x32x16_bf16(as_bf16x8(a), as_bf16x8(b), c, 0, 0, 0);
}

// ---------------- fused prep: 3 weight swizzles (32x32x16 A-frag order) + zero x ----------------
template <int COUT, int CIN, int CP, int K>
static __device__ __forceinline__ void prep_one(int t, const float* __restrict__ w,
                                                ushort_t* __restrict__ Wb) {
    constexpr int NC = CP / 16;
    constexpr int NS = K * NC;
    int j = t & 7;
    int lane = (t >> 3) & 63;
    int s = (t >> 9) % NS;
    int ct = (t >> 9) / NS;
    int co = ct * 32 + (lane & 31);
    int tt = s / NC, cc = s % NC;
    int ci = cc * 16 + ((lane >> 5) & 1) * 8 + j;
    float v = 0.f;
    if (co < COUT && ci < CIN) v = w[((size_t)co * CIN + ci) * K + tt];
    Wb[t] = f2bf(v);
}

#define PREP_T0 (4 * 12 * 512)
#define PREP_T1 (PREP_T0 + 4 * 30 * 512)
#define PREP_T2 (PREP_T1 + 8 * 56 * 512)
#define PREP_T3 (PREP_T2 + 51200)

__global__ __launch_bounds__(256) void k_prep_all(
        const float* __restrict__ c0w, const float* __restrict__ c1w,
        const float* __restrict__ c2w, float* __restrict__ x,
        ushort_t* __restrict__ Wb0, ushort_t* __restrict__ Wb1,
        ushort_t* __restrict__ Wb2) {
    int tid = blockIdx.x * 256 + threadIdx.x;
    if (tid < PREP_T0) prep_one<96, 50, 64, 3>(tid, c0w, Wb0);
    else if (tid < PREP_T1) prep_one<128, 96, 96, 5>(tid - PREP_T0, c1w, Wb1);
    else if (tid < PREP_T2) prep_one<200, 128, 128, 7>(tid - PREP_T1, c2w, Wb2);
    else if (tid < PREP_T3) x[tid - PREP_T2] = 0.f;
}

// ---------------- MFMA conv1d body, 32x32x16, deep rolling prefetch ----------------
// Wave = 64co(ct=2) x 64l(lt=2). Block = CO_WAVES x L_WAVES waves.
// A (weights) from L2 with prefetch distance 4 (covers ~200cyc L2 latency at
// ~32 MFMA cyc/step x ~3 waves/SIMD); B (LDS) with distance 2.
// EMB: build X tile directly from seq+emb. FMAX: relu+maxpool -> atomicMax.
template <int CP, int K, int COUT, int CO_WAVES, int L_WAVES, bool FMAX, bool EMB>
static __device__ __forceinline__ void conv_body(
        const ushort_t* __restrict__ act, const int* __restrict__ seq,
        const float* __restrict__ emb, const ushort_t* __restrict__ Wb,
        const float* __restrict__ bias, void* __restrict__ outv,
        ushort_t* __restrict__ Xs) {
    constexpr int NC = CP / 16;
    constexpr int NS = K * NC;
    constexpr int P = K / 2;
    constexpr int PITCH = CP + 8;     // ushorts; 16B-aligned rows, non-pow2 bank stride
    constexpr int LTILE = 64 * L_WAVES;
    constexpr int ROWS = LTILE + K - 1;
    constexpr int CPR = CP / 8;
    constexpr int PFA = (NS < 4) ? NS : 4;  // A prefetch distance
    constexpr int PFB = (NS < 2) ? NS : 2;  // B prefetch distance

    int b = blockIdx.z, lb = blockIdx.x;
    int l0 = lb * LTILE;
    int tid = threadIdx.x;

    // ---- stage X tile (halo, zero-padded at edges) ----
    if (EMB) {
        const int* seqb = seq + (size_t)b * LP;
        for (int idx = tid; idx < ROWS * CPR; idx += 256) {
            int r = idx / CPR, c = idx % CPR;
            int l = l0 - P + r;
            uint4 v = {0u, 0u, 0u, 0u};
            if ((unsigned)l < (unsigned)LP) {
                int s = seqb[l];
                const float* e = emb + (size_t)s * 50;
                ushort_t h[8];
#pragma unroll
                for (int j = 0; j < 8; ++j) {
                    int cc = c * 8 + j;
                    h[j] = (cc < 50) ? f2bf(e[cc]) : (ushort_t)0;
                }
                v.x = (unsigned)h[0] | ((unsigned)h[1] << 16);
                v.y = (unsigned)h[2] | ((unsigned)h[3] << 16);
                v.z = (unsigned)h[4] | ((unsigned)h[5] << 16);
                v.w = (unsigned)h[6] | ((unsigned)h[7] << 16);
            }
            *(uint4*)(Xs + r * PITCH + c * 8) = v;
        }
    } else {
        const ushort_t* actb = act + (size_t)b * LP * CP;
        for (int idx = tid; idx < ROWS * CPR; idx += 256) {
            int r = idx / CPR, c = idx % CPR;
            int l = l0 - P + r;
            uint4 v = {0u, 0u, 0u, 0u};
            if ((unsigned)l < (unsigned)LP) v = *(const uint4*)(actb + (size_t)l * CP + c * 8);
            *(uint4*)(Xs + r * PITCH + c * 8) = v;
        }
    }

    int lane = tid & 63, wv = tid >> 6;
    int cw = wv % CO_WAVES, lw = wv / CO_WAVES;
    int ln31 = lane & 31, half = lane >> 5;

    // A stream: fragment (tile, s) at Wb + ((tile*NS + s)*64 + lane) uint4s
    const uint4* A0 = (const uint4*)Wb + ((size_t)(cw * 2) * NS) * 64 + lane;
    // B base (ushort idx): row = lw*64 + lt*32 + ln31 + t, col = cc*16 + half*8
    int bbase = (lw * 64 + ln31) * PITCH + half * 8;

    f32x16 acc[2][2];
#pragma unroll
    for (int ct = 0; ct < 2; ++ct)
#pragma unroll
        for (int lt = 0; lt < 2; ++lt)
#pragma unroll
            for (int r = 0; r < 16; ++r) acc[ct][lt][r] = 0.f;

    __syncthreads();

    // Rolling prefetch buffers; fully unrolled loop -> SSA registers, live range =
    // prefetch distance (A: 2x4 uint4 = 32 regs, B: 2x2 uint4 = 16 regs).
    uint4 a0b[NS], a1b[NS], b0b[NS], b1b[NS];
#pragma unroll
    for (int s = 0; s < PFA; ++s) {
        a0b[s] = A0[(size_t)s * 64];
        a1b[s] = A0[(size_t)(NS + s) * 64];
    }
#pragma unroll
    for (int s = 0; s < PFB; ++s) {
        int t = s / NC, cc = s % NC;
        int off = bbase + t * PITCH + cc * 16;
        b0b[s] = *(const uint4*)(Xs + off);
        b1b[s] = *(const uint4*)(Xs + off + 32 * PITCH);
    }
#pragma unroll
    for (int s = 0; s < NS; ++s) {
        if (s + PFA < NS) {
            a0b[s + PFA] = A0[(size_t)(s + PFA) * 64];
            a1b[s + PFA] = A0[(size_t)(NS + s + PFA) * 64];
        }
        if (s + PFB < NS) {
            int sn = s + PFB;
            int tn = sn / NC, ccn = sn % NC;
            int off = bbase + tn * PITCH + ccn * 16;
            b0b[sn] = *(const uint4*)(Xs + off);
            b1b[sn] = *(const uint4*)(Xs + off + 32 * PITCH);
        }
        acc[0][0] = mfma32(a0b[s], b0b[s], acc[0][0]);
        acc[1][0] = mfma32(a1b[s], b0b[s], acc[1][0]);
        acc[0][1] = mfma32(a0b[s], b1b[s], acc[0][1]);
        acc[1][1] = mfma32(a1b[s], b1b[s], acc[1][1]);
    }

    // C/D layout: col(l) = lane&31, row(co within tile) = (r&3) + 8*(r>>2) + 4*half
    if (!FMAX) {
        ushort_t* out = (ushort_t*)outv + (size_t)b * LP * COUT;
#pragma unroll
        for (int ct = 0; ct < 2; ++ct) {
            int cbase = (cw * 2 + ct) * 32 + 4 * half;
#pragma unroll
            for (int g = 0; g < 4; ++g) {
                int co = cbase + 8 * g;
                if (co >= COUT) continue;
                float4 bv = *(const float4*)(bias + co);
#pragma unroll
                for (int lt = 0; lt < 2; ++lt) {
                    int l = l0 + lw * 64 + lt * 32 + ln31;
                    if (l < LP) {
                        ushort_t h0 = f2bf(fmaxf(acc[ct][lt][4 * g + 0] + bv.x, 0.f));
                        ushort_t h1 = f2bf(fmaxf(acc[ct][lt][4 * g + 1] + bv.y, 0.f));
                        ushort_t h2 = f2bf(fmaxf(acc[ct][lt][4 * g + 2] + bv.z, 0.f));
                        ushort_t h3 = f2bf(fmaxf(acc[ct][lt][4 * g + 3] + bv.w, 0.f));
                        uint2 o;
                        o.x = (unsigned)h0 | ((unsigned)h1 << 16);
                        o.y = (unsigned)h2 | ((unsigned)h3 << 16);
                        *(uint2*)(out + (size_t)l * COUT + co) = o;
                    }
                }
            }
        }
    } else {
        float* xout = (float*)outv;
#pragma unroll
        for (int ct = 0; ct < 2; ++ct) {
            float mx[16];
#pragma unroll
            for (int r = 0; r < 16; ++r) mx[r] = -3.0e38f;
#pragma unroll
            for (int lt = 0; lt < 2; ++lt) {
                int l = l0 + lw * 64 + lt * 32 + ln31;
                if (l < LP) {
#pragma unroll
                    for (int r = 0; r < 16; ++r) mx[r] = fmaxf(mx[r], acc[ct][lt][r]);
                }
            }
#pragma unroll
            for (int r = 0; r < 16; ++r) {
#pragma unroll
                for (int off = 1; off < 32; off <<= 1)
                    mx[r] = fmaxf(mx[r], __shfl_xor(mx[r], off, 64));
            }
            if (ln31 == 0) {
                int cbase = (cw * 2 + ct) * 32 + 4 * half;
#pragma unroll
                for (int r = 0; r < 16; ++r) {
                    int co = cbase + (r & 3) + 8 * (r >> 2);
                    if (co < COUT) {
                        float v = fmaxf(mx[r] + bias[co], 0.f);
                        atomicMax((int*)&xout[(size_t)b * 400 + 200 + co], __float_as_int(v));
                    }
                }
            }
        }
    }
}

// Distinct names so rocprof disambiguates the tower.
__global__ __launch_bounds__(256, 3) void k_conv0(
        const int* __restrict__ seq, const float* __restrict__ emb,
        const ushort_t* __restrict__ Wb, const float* __restrict__ bias,
        ushort_t* __restrict__ out) {
    __shared__ __align__(16) ushort_t Xs[(128 + 2) * (64 + 8)];
    conv_body<64, 3, 96, 2, 2, false, true>(nullptr, seq, emb, Wb, bias, out, Xs);
}
__global__ __launch_bounds__(256, 3) void k_conv1(
        const ushort_t* __restrict__ act, const ushort_t* __restrict__ Wb,
        const float* __restrict__ bias, ushort_t* __restrict__ out) {
    __shared__ __align__(16) ushort_t Xs[(128 + 4) * (96 + 8)];
    conv_body<96, 5, 128, 2, 2, false, false>(act, nullptr, nullptr, Wb, bias, out, Xs);
}
__global__ __launch_bounds__(256, 3) void k_conv2(
        const ushort_t* __restrict__ act, const ushort_t* __restrict__ Wb,
        const float* __restrict__ bias, float* __restrict__ x) {
    __shared__ __align__(16) ushort_t Xs[(64 + 6) * (128 + 8)];
    conv_body<128, 7, 200, 4, 1, true, false>(act, nullptr, nullptr, Wb, bias, x, Xs);
}

// ---------------- binput = fbonds @ W_i ; msg = relu(binput) ----------------
__global__ __launch_bounds__(256) void k_bond_input(
        const float* __restrict__ fbonds, const float* __restrict__ Wi,
        float* __restrict__ binput, float* __restrict__ msg) {
    int bond0 = blockIdx.x * BIPB;
    __shared__ float fb[BIPB][BFD];
    int tid = threadIdx.x;
    if (tid < BIPB * BFD) fb[tid / BFD][tid % BFD] = fbonds[(size_t)bond0 * BFD + tid];
    __syncthreads();
    if (tid < H) {
        float acc[BIPB];
#pragma unroll
        for (int q = 0; q < BIPB; ++q) acc[q] = 0.f;
#pragma unroll 5
        for (int k = 0; k < BFD; ++k) {
            float w = Wi[k * H + tid];
#pragma unroll
            for (int q = 0; q < BIPB; ++q) acc[q] += fb[q][k] * w;
        }
#pragma unroll
        for (int q = 0; q < BIPB; ++q) {
            size_t o = (size_t)(bond0 + q) * H + tid;
            binput[o] = acc[q];
            msg[o] = fmaxf(acc[q], 0.f);
        }
    }
}

// ---------------- message update: msgOut = relu(binput + (sum nei) @ W_h) ----------------
__global__ __launch_bounds__(256) void k_msg(
        const float* __restrict__ msgIn, const float* __restrict__ binput,
        const int* __restrict__ bgraph, const float* __restrict__ Wh,
        float* __restrict__ msgOut) {
    const int grpPerMol = NBB / BPB;
    int b = blockIdx.x / grpPerMol;
    int grp = blockIdx.x % grpPerMol;
    int bond0 = grp * BPB;
    __shared__ int idxs[BPB * 6];
    __shared__ float nei[BPB][H];
    int tid = threadIdx.x;
    if (tid < BPB * 6) idxs[tid] = bgraph[((size_t)(b * NBB + bond0)) * 6 + tid];
    __syncthreads();
    if (tid < H) {
        const float* base = msgIn + (size_t)b * NBB * H;
#pragma unroll
        for (int q = 0; q < BPB; ++q) {
            float s = 0.f;
#pragma unroll
            for (int j = 0; j < 6; ++j) s += base[(size_t)idxs[q * 6 + j] * H + tid];
            nei[q][tid] = s;
        }
    }
    __syncthreads();
    if (tid < H) {
        float acc[BPB];
#pragma unroll
        for (int q = 0; q < BPB; ++q)
            acc[q] = binput[((size_t)(b * NBB + bond0 + q)) * H + tid];
#pragma unroll 4
        for (int hi = 0; hi < H; ++hi) {
            float w = Wh[hi * H + tid];
#pragma unroll
            for (int q = 0; q < BPB; ++q) acc[q] += nei[q][hi] * w;
        }
#pragma unroll
        for (int q = 0; q < BPB; ++q)
            msgOut[((size_t)(b * NBB + bond0 + q)) * H + tid] = fmaxf(acc[q], 0.f);
    }
}

// ---------------- atom head: relu(cat(fa, nei) @ W_o + b), mean -> x[:, :200] ----------------
__global__ __launch_bounds__(256) void k_atom(
        const float* __restrict__ msg, const float* __restrict__ fatoms,
        const int* __restrict__ agraph, const float* __restrict__ Wo,
        const float* __restrict__ Wob, float* __restrict__ x) {
    const int grpPerMol = NA / APB;
    int b = blockIdx.x / grpPerMol;
    int grp = blockIdx.x % grpPerMol;
    int atom0 = grp * APB;
    __shared__ int idxs[APB * 6];
    __shared__ float cat[APB][CATD];
    int tid = threadIdx.x;
    if (tid < APB * 6) idxs[tid] = agraph[((size_t)(b * NA + atom0)) * 6 + tid];
    if (tid >= 64 && tid < 64 + APB * AFD) {
        int t = tid - 64;
        int q = t / AFD, c = t % AFD;
        cat[q][c] = fatoms[((size_t)(b * NA + atom0 + q)) * AFD + c];
    }
    __syncthreads();
    if (tid < H) {
        const float* base = msg + (size_t)b * NBB * H;
#pragma unroll
        for (int q = 0; q < APB; ++q) {
            float s = 0.f;
#pragma unroll
            for (int j = 0; j < 6; ++j) s += base[(size_t)idxs[q * 6 + j] * H + tid];
            cat[q][AFD + tid] = s;
        }
    }
    __syncthreads();
    if (tid < H) {
        float bb = Wob[tid];
        float acc0 = bb, acc1 = bb;
#pragma unroll 4
        for (int k = 0; k < CATD; ++k) {
            float w = Wo[k * H + tid];
            acc0 += cat[0][k] * w;
            acc1 += cat[1][k] * w;
        }
        atomicAdd(&x[(size_t)b * 400 + tid],
                  (fmaxf(acc0, 0.f) + fmaxf(acc1, 0.f)) * (1.f / NA));
    }
}

// ---------------- fused FC head: 400 -> 200 -> 100 -> 1 ----------------
__global__ __launch_bounds__(256) void k_fc(
        const float* __restrict__ x,
        const float* __restrict__ w0, const float* __restrict__ b0,
        const float* __restrict__ w1, const float* __restrict__ b1,
        const float* __restrict__ w2, const float* __restrict__ b2,
        float* __restrict__ out) {
    int b = blockIdx.x, tid = threadIdx.x;
    __shared__ float xr[400];
    __shared__ float h1[200];
    __shared__ float h2[100];
    for (int i = tid; i < 400; i += 256) xr[i] = x[(size_t)b * 400 + i];
    __syncthreads();
    if (tid < 200) {
        float a = b0[tid];
#pragma unroll 4
        for (int k = 0; k < 400; ++k) a += xr[k] * w0[k * 200 + tid];
        h1[tid] = fmaxf(a, 0.f);
    }
    __syncthreads();
    if (tid < 100) {
        float a = b1[tid];
#pragma unroll 4
        for (int k = 0; k < 200; ++k) a += h1[k] * w1[k * 100 + tid];
        h2[tid] = fmaxf(a, 0.f);
    }
    __syncthreads();
    if (tid == 0) {
        float a = b2[0];
#pragma unroll 4
        for (int k = 0; k < 100; ++k) a += h2[k] * w2[k];
        out[b] = a;
    }
}

extern "C" void kernel_launch(void* const* d_in, const int* in_sizes, int n_in,
                              void* d_out, int out_size, void* d_ws, size_t ws_size,
                              hipStream_t stream) {
    const float* fatoms = (const float*)d_in[0];
    const float* fbonds = (const float*)d_in[1];
    const int* agraph = (const int*)d_in[2];
    const int* bgraph = (const int*)d_in[3];
    const int* seq = (const int*)d_in[4];
    const float* Wi = (const float*)d_in[5];
    const float* Wh = (const float*)d_in[6];
    const float* Wo = (const float*)d_in[7];
    const float* Wob = (const float*)d_in[8];
    const float* embp = (const float*)d_in[9];
    const float* c0w = (const float*)d_in[10];
    const float* c0b = (const float*)d_in[11];
    const float* c1w = (const float*)d_in[12];
    const float* c1b = (const float*)d_in[13];
    const float* c2w = (const float*)d_in[14];
    const float* c2b = (const float*)d_in[15];
    const float* fc0w = (const float*)d_in[16];
    const float* fc0b = (const float*)d_in[17];
    const float* fc1w = (const float*)d_in[18];
    const float* fc1b = (const float*)d_in[19];
    const float* fc2w = (const float*)d_in[20];
    const float* fc2b = (const float*)d_in[21];

    float* ws = (float*)d_ws;
    float* binput = ws;                    // 2457600
    float* msgA = binput + 2457600;        // 2457600
    float* msgB = msgA + 2457600;          // 2457600
    float* x = msgB + 2457600;             // 51200
    ushort_t* u = (ushort_t*)(x + 51200);  // bf16 region
    ushort_t* act1 = u;                    // 128000*96  = 12288000
    ushort_t* act2 = act1 + 12288000;      // 128000*128 = 16384000
    ushort_t* Wb0 = act2 + 16384000;       // 4*12*512  = 24576
    ushort_t* Wb1 = Wb0 + 24576;           // 4*30*512  = 61440
    ushort_t* Wb2 = Wb1 + 61440;           // 8*56*512  = 229376

    // fused: weight swizzles + zero x (k_atom atomicAdd / conv2 atomicMax need zeros)
    k_prep_all<<<(PREP_T3 + 255) / 256, 256, 0, stream>>>(c0w, c1w, c2w, x, Wb0, Wb1, Wb2);

    // ---- MPNN ----
    k_bond_input<<<BATCH * NBB / BIPB, 256, 0, stream>>>(fbonds, Wi, binput, msgA);
    k_msg<<<BATCH * NBB / BPB, 256, 0, stream>>>(msgA, binput, bgraph, Wh, msgB);
    k_msg<<<BATCH * NBB / BPB, 256, 0, stream>>>(msgB, binput, bgraph, Wh, msgA);
    k_atom<<<BATCH * NA / APB, 256, 0, stream>>>(msgA, fatoms, agraph, Wo, Wob, x);

    // ---- protein tower (bf16 MFMA, 32x32x16, deep prefetch; conv0 fuses embedding) ----
    k_conv0<<<dim3(8, 1, BATCH), 256, 0, stream>>>(seq, embp, Wb0, c0b, act1);
    k_conv1<<<dim3(8, 1, BATCH), 256, 0, stream>>>(act1, Wb1, c1b, act2);
    k_conv2<<<dim3(16, 1, BATCH), 256, 0, stream>>>(act2, Wb2, c2b, x);

    // ---- fused FC head ----
    k_fc<<<BATCH, 256, 0, stream>>>(x, fc0w, fc0b, fc1w, fc1b, fc2w, fc2b, (float*)d_out);
}